// Round 8
// baseline (374.176 us; speedup 1.0000x reference)
//
#include <hip/hip_runtime.h>
#include <hip/hip_fp16.h>
#include <math.h>

#define N_NODES 50000
#define N_EDGES 800000
#define N_GRAPHS 512
#define CAP 62    // slots per 128B bucket record; P(Poisson(16) > 62) ~ 1e-18
#define NPART 8   // one partition per XCD
#define PSIZE ((N_NODES + NPART - 1) / NPART)  // 6250
#define ECHUNK 1024

typedef unsigned short u16;
typedef unsigned int u32;
typedef __attribute__((ext_vector_type(8))) short bf16x8_t;
typedef __attribute__((ext_vector_type(4))) float f32x4_t;

constexpr int NCHUNK = (N_EDGES + ECHUNK - 1) / ECHUNK;  // 782

// ---- bf16 helpers (RTNE, finite values only) ----
__device__ __forceinline__ u16 f2bf(float f) {
    u32 u = __builtin_bit_cast(u32, f);
    return (u16)((u + 0x7fffu + ((u >> 16) & 1u)) >> 16);
}
__device__ __forceinline__ float bf2f(u16 s) {
    return __builtin_bit_cast(float, (u32)s << 16);
}
__device__ __forceinline__ float bf_lo(u32 u) { return __builtin_bit_cast(float, u << 16); }
__device__ __forceinline__ float bf_hi(u32 u) { return __builtin_bit_cast(float, u & 0xffff0000u); }

// ---------------- XCD-affine bucketed CSR fill ----------------
// Each block reads its REAL XCD id (HW_REG_XCC_ID, verified on gfx950) and
// processes only edges whose dst lies in that XCD's node partition, claiming
// 1024-edge chunks from a per-partition cursor. All atomics+stores to a given
// bucket line thus issue from ONE XCD: the line stays in its L2, writes merge,
// atomics are L2-local.
__global__ __launch_bounds__(256) void csr_fill_xcd(const int* __restrict__ src,
                                                    const int* __restrict__ dst,
                                                    u32* __restrict__ bucket,
                                                    int* __restrict__ claim) {
    __shared__ int schunk;
    int xcd;
    asm volatile("s_getreg_b32 %0, hwreg(HW_REG_XCC_ID)" : "=s"(xcd));
    xcd &= 7;
    const int nlo = xcd * PSIZE;
    const int nhi = nlo + PSIZE;
    u16* slots = reinterpret_cast<u16*>(bucket);
    for (;;) {
        if (threadIdx.x == 0) schunk = atomicAdd(&claim[xcd], 1);
        __syncthreads();
        int chunk = schunk;
        __syncthreads();
        if (chunk >= NCHUNK) break;
        int base = chunk * ECHUNK + threadIdx.x;
#pragma unroll
        for (int t = 0; t < ECHUNK / 256; t++) {
            int e = base + t * 256;
            if (e < N_EDGES) {
                int d = dst[e];
                if (d >= nlo && d < nhi) {
                    int s = src[e];
                    int pos = atomicAdd(&bucket[(size_t)d * 32], 1);
                    if (pos < CAP) slots[(size_t)d * 64 + 2 + pos] = (u16)s;
                }
            }
        }
    }
}

__global__ void compute_dis(const u32* __restrict__ bucket, float* __restrict__ dis) {
    int i = blockIdx.x * blockDim.x + threadIdx.x;
    if (i < N_NODES) dis[i] = 1.0f / sqrtf((float)bucket[(size_t)i * 32] + 1.0f);
}

// ---------------- conversions ----------------
__global__ void convert_x_bf16(const float* __restrict__ x, u16* __restrict__ xb) {
    int i = blockIdx.x * 256 + threadIdx.x;  // one float4 per thread
    if (i >= (N_NODES * 128) / 4) return;
    float4 v = reinterpret_cast<const float4*>(x)[i];
    u32 lo = (u32)f2bf(v.x) | ((u32)f2bf(v.y) << 16);
    u32 hi = (u32)f2bf(v.z) | ((u32)f2bf(v.w) << 16);
    reinterpret_cast<uint2*>(xb)[i] = make_uint2(lo, hi);
}

// all four W[K][N] f32 -> Wt[N][K] bf16 transposes in one launch
__global__ void convert_wT_all(const float* __restrict__ W1, u16* __restrict__ wt1,
                               const float* __restrict__ W2, u16* __restrict__ wt2,
                               const float* __restrict__ W3, u16* __restrict__ wt3,
                               const float* __restrict__ W4, u16* __restrict__ wt4) {
    int idx = blockIdx.x * 256 + threadIdx.x;
    const float* Wf;
    u16* Wt;
    int K, N, off;
    if (idx < 16384)      { Wf = W1; Wt = wt1; K = 128; N = 128; off = 0; }
    else if (idx < 24576) { Wf = W2; Wt = wt2; K = 128; N = 64;  off = 16384; }
    else if (idx < 32768) { Wf = W3; Wt = wt3; K = 64;  N = 128; off = 24576; }
    else if (idx < 49152) { Wf = W4; Wt = wt4; K = 128; N = 128; off = 32768; }
    else return;
    int t = idx - off;
    int k = t / N, n = t % N;
    Wt[n * K + k] = f2bf(Wf[t]);
}

// ---------------- bf16 MFMA GEMM: C[M,N] = A[M,K] @ Wt[N,K]^T (+bias, relu, row-scale) --------
template <int N, int K, bool BIAS, bool RELU, bool SCALE>
__global__ __launch_bounds__(256) void gemm_mfma(const u16* __restrict__ A,
                                                 const u16* __restrict__ Wt,
                                                 const float* __restrict__ bias,
                                                 const float* __restrict__ dis,
                                                 u16* __restrict__ C) {
    constexpr int KB = K / 32;
    constexpr int TN = N / 64;
    constexpr int TM = (N_NODES + 63) / 64;  // 782
    int wave = threadIdx.x >> 6;
    int lane = threadIdx.x & 63;
    int W = blockIdx.x * 4 + wave;
    if (W >= TM * TN) return;
    int tm = W / TN, tn = W % TN;
    int r16 = lane & 15;
    int kg = lane >> 4;

    bf16x8_t bf[4][KB];
#pragma unroll
    for (int nr = 0; nr < 4; nr++) {
        int colg = tn * 64 + nr * 16 + r16;
#pragma unroll
        for (int kb = 0; kb < KB; kb++)
            bf[nr][kb] = *reinterpret_cast<const bf16x8_t*>(Wt + (size_t)colg * K + kb * 32 + kg * 8);
    }

    f32x4_t acc[4][4];
#pragma unroll
    for (int mr = 0; mr < 4; mr++)
#pragma unroll
        for (int nr = 0; nr < 4; nr++)
#pragma unroll
            for (int t = 0; t < 4; t++) acc[mr][nr][t] = 0.f;

#pragma unroll
    for (int mr = 0; mr < 4; mr++) {
        int row = tm * 64 + mr * 16 + r16;
        if (row >= N_NODES) row = N_NODES - 1;
        bf16x8_t af[KB];
#pragma unroll
        for (int kb = 0; kb < KB; kb++)
            af[kb] = *reinterpret_cast<const bf16x8_t*>(A + (size_t)row * K + kb * 32 + kg * 8);
#pragma unroll
        for (int kb = 0; kb < KB; kb++)
#pragma unroll
            for (int nr = 0; nr < 4; nr++)
                acc[mr][nr] = __builtin_amdgcn_mfma_f32_16x16x32_bf16(af[kb], bf[nr][kb],
                                                                      acc[mr][nr], 0, 0, 0);
    }

#pragma unroll
    for (int mr = 0; mr < 4; mr++) {
        float sc[4];
#pragma unroll
        for (int r = 0; r < 4; r++) {
            int row = tm * 64 + mr * 16 + kg * 4 + r;
            sc[r] = (SCALE && row < N_NODES) ? dis[row] : 1.f;
        }
#pragma unroll
        for (int nr = 0; nr < 4; nr++) {
            int colg = tn * 64 + nr * 16 + r16;
            float bv = BIAS ? bias[colg] : 0.f;
#pragma unroll
            for (int r = 0; r < 4; r++) {
                int row = tm * 64 + mr * 16 + kg * 4 + r;
                if (row < N_NODES) {
                    float v = acc[mr][nr][r] + bv;
                    if (RELU) v = fmaxf(v, 0.f);
                    if (SCALE) v *= sc[r];
                    C[(size_t)row * N + colg] = f2bf(v);
                }
            }
        }
    }
}

// ---------------- propagate over pre-scaled rows h' = dis ⊙ h ----------------
template <int F, bool RELU, bool BIAS, bool WF32, bool WBF16, bool SCALEOUT>
__global__ __launch_bounds__(256) void propagate_b(const u16* __restrict__ h,
                                                   const u32* __restrict__ bucket,
                                                   const float* __restrict__ dis,
                                                   const float* __restrict__ bias,
                                                   float* __restrict__ out_f,
                                                   u16* __restrict__ out_b) {
    int w = (blockIdx.x * blockDim.x + threadIdx.x) >> 6;
    int lane = threadIdx.x & 63;
    if (w >= N_NODES) return;
    const u32* bw = bucket + (size_t)w * 32;
    int deg = __builtin_amdgcn_readfirstlane(min((int)bw[0], CAP));
    const u16* slots = reinterpret_cast<const u16*>(bw) + 2;
    const u32* sw = reinterpret_cast<const u32*>(reinterpret_cast<const char*>(bw) + 4);
    float di = dis[w];

    if (F == 128) {
        const u32* hw = reinterpret_cast<const u32*>(h);  // 64 u32 per row
        float2 a0 = {0.f, 0.f}, a1 = {0.f, 0.f}, a2 = {0.f, 0.f}, a3 = {0.f, 0.f};
        int i = 0;
        for (; i + 16 <= deg; i += 16) {
            u32 cw[8], hv[16];
#pragma unroll
            for (int j = 0; j < 8; j++) cw[j] = sw[(i >> 1) + j];
#pragma unroll
            for (int j = 0; j < 8; j++) {
                hv[2 * j]     = hw[(size_t)(cw[j] & 0xffffu) * 64 + lane];
                hv[2 * j + 1] = hw[(size_t)(cw[j] >> 16) * 64 + lane];
            }
#pragma unroll
            for (int j = 0; j < 16; j++) {
                float lo = bf_lo(hv[j]), hi = bf_hi(hv[j]);
                if ((j & 3) == 0) { a0.x += lo; a0.y += hi; }
                else if ((j & 3) == 1) { a1.x += lo; a1.y += hi; }
                else if ((j & 3) == 2) { a2.x += lo; a2.y += hi; }
                else { a3.x += lo; a3.y += hi; }
            }
        }
        for (; i + 8 <= deg; i += 8) {
            u32 cw[4], hv[8];
#pragma unroll
            for (int j = 0; j < 4; j++) cw[j] = sw[(i >> 1) + j];
#pragma unroll
            for (int j = 0; j < 4; j++) {
                hv[2 * j]     = hw[(size_t)(cw[j] & 0xffffu) * 64 + lane];
                hv[2 * j + 1] = hw[(size_t)(cw[j] >> 16) * 64 + lane];
            }
#pragma unroll
            for (int j = 0; j < 8; j++) {
                float lo = bf_lo(hv[j]), hi = bf_hi(hv[j]);
                if ((j & 3) == 0) { a0.x += lo; a0.y += hi; }
                else if ((j & 3) == 1) { a1.x += lo; a1.y += hi; }
                else if ((j & 3) == 2) { a2.x += lo; a2.y += hi; }
                else { a3.x += lo; a3.y += hi; }
            }
        }
        for (; i < deg; i++) {
            u32 u = hw[(size_t)slots[i] * 64 + lane];
            a0.x += bf_lo(u);
            a0.y += bf_hi(u);
        }
        u32 su = hw[(size_t)w * 64 + lane];
        float ox = (a0.x + a1.x + a2.x + a3.x + bf_lo(su)) * di;
        float oy = (a0.y + a1.y + a2.y + a3.y + bf_hi(su)) * di;
        if (BIAS) {
            float2 bv = reinterpret_cast<const float2*>(bias)[lane];
            ox += bv.x;
            oy += bv.y;
        }
        if (RELU) { ox = fmaxf(ox, 0.f); oy = fmaxf(oy, 0.f); }
        if (WF32) {
            reinterpret_cast<float2*>(out_f + (size_t)w * 128)[lane] = make_float2(ox, oy);
        }
        if (WBF16) {
            float wx = SCALEOUT ? ox * di : ox;
            float wy = SCALEOUT ? oy * di : oy;
            u32 pk = (u32)f2bf(wx) | ((u32)f2bf(wy) << 16);
            reinterpret_cast<u32*>(out_b)[(size_t)w * 64 + lane] = pk;
        }
    } else {
        float a0 = 0.f, a1 = 0.f, a2 = 0.f, a3 = 0.f;
        int i = 0;
        for (; i + 16 <= deg; i += 16) {
            u32 cw[8];
            u16 hv[16];
#pragma unroll
            for (int j = 0; j < 8; j++) cw[j] = sw[(i >> 1) + j];
#pragma unroll
            for (int j = 0; j < 8; j++) {
                hv[2 * j]     = h[(size_t)(cw[j] & 0xffffu) * 64 + lane];
                hv[2 * j + 1] = h[(size_t)(cw[j] >> 16) * 64 + lane];
            }
#pragma unroll
            for (int j = 0; j < 16; j++) {
                float v = bf2f(hv[j]);
                if ((j & 3) == 0) a0 += v;
                else if ((j & 3) == 1) a1 += v;
                else if ((j & 3) == 2) a2 += v;
                else a3 += v;
            }
        }
        for (; i + 8 <= deg; i += 8) {
            u32 cw[4];
            u16 hv[8];
#pragma unroll
            for (int j = 0; j < 4; j++) cw[j] = sw[(i >> 1) + j];
#pragma unroll
            for (int j = 0; j < 4; j++) {
                hv[2 * j]     = h[(size_t)(cw[j] & 0xffffu) * 64 + lane];
                hv[2 * j + 1] = h[(size_t)(cw[j] >> 16) * 64 + lane];
            }
#pragma unroll
            for (int j = 0; j < 8; j++) {
                float v = bf2f(hv[j]);
                if ((j & 3) == 0) a0 += v;
                else if ((j & 3) == 1) a1 += v;
                else if ((j & 3) == 2) a2 += v;
                else a3 += v;
            }
        }
        for (; i < deg; i++) a0 += bf2f(h[(size_t)slots[i] * 64 + lane]);
        float o = (a0 + a1 + a2 + a3 + bf2f(h[(size_t)w * 64 + lane])) * di;
        if (BIAS) o += bias[lane];
        if (RELU) o = fmaxf(o, 0.f);
        if (WF32) out_f[(size_t)w * 64 + lane] = o;
        if (WBF16) out_b[(size_t)w * 64 + lane] = f2bf(SCALEOUT ? o * di : o);
    }
}

// ---------------- scatter-mean pooling: one block (4 waves) per graph ----------------
__global__ __launch_bounds__(256) void pool_kernel(const float* __restrict__ z,
                                                   const int* __restrict__ batch,
                                                   float* __restrict__ agg) {
    __shared__ float part[3][64];
    int g = blockIdx.x;
    int wave = threadIdx.x >> 6;
    int lane = threadIdx.x & 63;
    int l = 0, h = N_NODES;
    while (l < h) { int m = (l + h) >> 1; if (batch[m] < g) l = m + 1; else h = m; }
    int s = l;
    h = N_NODES;
    while (l < h) { int m = (l + h) >> 1; if (batch[m] < g + 1) l = m + 1; else h = m; }
    int e = l;
    float acc = 0.f;
    for (int i = s + wave; i < e; i += 4) acc += z[(size_t)i * 64 + lane];
    if (wave) part[wave - 1][lane] = acc;
    __syncthreads();
    if (wave == 0) {
        acc += part[0][lane] + part[1][lane] + part[2][lane];
        agg[(size_t)g * 64 + lane] = acc / fmaxf((float)(e - s), 1.0f);
    }
}

extern "C" void kernel_launch(void* const* d_in, const int* in_sizes, int n_in,
                              void* d_out, int out_size, void* d_ws, size_t ws_size,
                              hipStream_t stream) {
    const float* x   = (const float*)d_in[0];
    const int* eidx  = (const int*)d_in[1];
    const int* batch = (const int*)d_in[2];
    const float* W1  = (const float*)d_in[3];
    const float* b1  = (const float*)d_in[4];
    const float* W2  = (const float*)d_in[5];
    const float* b2  = (const float*)d_in[6];
    const float* W3  = (const float*)d_in[7];
    const float* b3  = (const float*)d_in[8];
    const float* W4  = (const float*)d_in[9];
    const float* b4  = (const float*)d_in[10];

    const int* src = eidx;
    const int* dst = eidx + N_EDGES;

    float* out_xhat = (float*)d_out;
    float* out_z    = out_xhat + (size_t)N_NODES * 128;
    float* out_agg  = out_z + (size_t)N_NODES * 64;

    char* p = (char*)d_ws;
    auto alloc = [&](size_t bytes) { char* r = p; p += (bytes + 255) & ~(size_t)255; return r; };
    u16* arena0 = (u16*)alloc((size_t)N_NODES * 128 * 2);   // 12.8 MB
    u16* arena1 = (u16*)alloc((size_t)N_NODES * 128 * 2);   // 12.8 MB
    u16* c1     = (u16*)alloc((size_t)N_NODES * 64 * 2);    // 6.4 MB
    u16* c2     = (u16*)alloc((size_t)N_NODES * 64 * 2);    // 6.4 MB
    u16* wt1    = (u16*)alloc(128 * 128 * 2);
    u16* wt2    = (u16*)alloc(128 * 64 * 2);
    u16* wt3    = (u16*)alloc(64 * 128 * 2);
    u16* wt4    = (u16*)alloc(128 * 128 * 2);
    u32* bucket = (u32*)alloc((size_t)N_NODES * 128);       // 6.4 MB, 128B records
    int* claim  = (int*)alloc(NPART * 4);                   // adjacent to bucket
    float* dis  = (float*)alloc(N_NODES * 4);

    // preprocessing: zero buckets + claim cursors (adjacent), XCD-affine fill
    hipMemsetAsync(bucket, 0, (size_t)N_NODES * 128 + 256, stream);
    csr_fill_xcd<<<2048, 256, 0, stream>>>(src, dst, bucket, claim);
    compute_dis<<<(N_NODES + 255) / 256, 256, 0, stream>>>(bucket, dis);

    convert_x_bf16<<<(N_NODES * 128 / 4 + 255) / 256, 256, 0, stream>>>(x, arena0);
    convert_wT_all<<<(49152 + 255) / 256, 256, 0, stream>>>(W1, wt1, W2, wt2, W3, wt3, W4, wt4);

    const int PROP_GRID = (N_NODES + 3) / 4;             // 12500
    const int G128 = ((N_NODES + 63) / 64 * 2 + 3) / 4;  // 391
    const int G64  = ((N_NODES + 63) / 64 * 1 + 3) / 4;  // 196

    // L1: C1' = dis ⊙ (x W1); h1 = relu(di*(Σ C1'[col] + C1'[w]) + b1)
    gemm_mfma<128, 128, false, false, true><<<G128, 256, 0, stream>>>(arena0, wt1, nullptr, dis, arena1);
    propagate_b<128, true, true, false, true, false><<<PROP_GRID, 256, 0, stream>>>(
        arena1, bucket, dis, b1, nullptr, arena0);
    // L2: C2' = dis ⊙ (h1 W2); z = di*(Σ C2'[col] + C2'[w]) + b2 ; c2 = dis ⊙ z (bf16)
    gemm_mfma<64, 128, false, false, true><<<G64, 256, 0, stream>>>(arena0, wt2, nullptr, dis, c1);
    propagate_b<64, false, true, true, true, true><<<PROP_GRID, 256, 0, stream>>>(
        c1, bucket, dis, b2, out_z, c2);
    pool_kernel<<<N_GRAPHS, 256, 0, stream>>>(out_z, batch, out_agg);
    // L3: t = P z  (gathers c2 = dis ⊙ z);  h2 = relu(t W3 + b3)
    propagate_b<64, false, false, false, true, false><<<PROP_GRID, 256, 0, stream>>>(
        c2, bucket, dis, nullptr, nullptr, c1);
    gemm_mfma<128, 64, true, true, false><<<G128, 256, 0, stream>>>(c1, wt3, b3, dis, arena1);
    // L4: C4' = dis ⊙ (h2 W4); x_hat = di*(Σ C4'[col] + C4'[w]) + b4
    gemm_mfma<128, 128, false, false, true><<<G128, 256, 0, stream>>>(arena1, wt4, nullptr, dis, arena0);
    propagate_b<128, false, true, true, false, false><<<PROP_GRID, 256, 0, stream>>>(
        arena0, bucket, dis, b4, out_xhat, nullptr);
}

// Round 9
// 267.046 us; speedup vs baseline: 1.4012x; 1.4012x over previous
//
#include <hip/hip_runtime.h>
#include <hip/hip_fp16.h>
#include <math.h>

#define N_NODES 50000
#define N_EDGES 800000
#define N_GRAPHS 512
#define CAP 62      // u16 slots per 128B bucket record; max degree (Poisson 16) ~45
#define NBINS 196   // bin = dst>>8 ; 196 bins of 256 nodes
#define CAPB 5120   // bin list capacity (expected 4081, sigma ~64)
#define ABLK 1024   // edges per bin_scatter block

typedef unsigned short u16;
typedef unsigned int u32;
typedef __attribute__((ext_vector_type(8))) short bf16x8_t;
typedef __attribute__((ext_vector_type(4))) float f32x4_t;

constexpr int NBLK_A = (N_EDGES + ABLK - 1) / ABLK;  // 782

// ---- bf16 helpers (RTNE, finite values only) ----
__device__ __forceinline__ u16 f2bf(float f) {
    u32 u = __builtin_bit_cast(u32, f);
    return (u16)((u + 0x7fffu + ((u >> 16) & 1u)) >> 16);
}
__device__ __forceinline__ float bf2f(u16 s) {
    return __builtin_bit_cast(float, (u32)s << 16);
}
__device__ __forceinline__ float bf_lo(u32 u) { return __builtin_bit_cast(float, u << 16); }
__device__ __forceinline__ float bf_hi(u32 u) { return __builtin_bit_cast(float, u & 0xffff0000u); }

// ---------------- block-wide exclusive scan helper (256 threads) ----------------
__device__ __forceinline__ int block_exscan(int val, int* lds, int tid) {
    lds[tid] = val;
    __syncthreads();
#pragma unroll
    for (int off = 1; off < 256; off <<= 1) {
        int t = (tid >= off) ? lds[tid - off] : 0;
        __syncthreads();
        lds[tid] += t;
        __syncthreads();
    }
    return lds[tid] - val;
}

// ---------------- pass 1: bin edges by dst>>8, LDS-staged run writes ----------------
// binCnt padded: counter b at binCnt[b*16] (one per 64B line).
__global__ __launch_bounds__(256) void bin_scatter(const int* __restrict__ src,
                                                   const int* __restrict__ dst,
                                                   u32* __restrict__ binCnt,
                                                   u32* __restrict__ binList) {
    __shared__ int cur[NBINS];
    __shared__ int lsStart[NBINS];
    __shared__ int gbase[NBINS];
    __shared__ int scanbuf[256];
    __shared__ u32 stage[ABLK];
    __shared__ int gpos[ABLK];
    int t = threadIdx.x;
    int e0 = blockIdx.x * ABLK;
    int nEdge = min(ABLK, N_EDGES - e0);  // 1024 or 256 (last block), multiple of 4

    for (int i = t; i < NBINS; i += 256) cur[i] = 0;
    __syncthreads();

    int myBin[4], myRank[4];
    u32 myPack[4];
    int nmy = 0;
    if (t * 4 < nEdge) {
        nmy = 4;
        int4 dv = *reinterpret_cast<const int4*>(dst + e0 + t * 4);
        int4 sv = *reinterpret_cast<const int4*>(src + e0 + t * 4);
        int ds[4] = {dv.x, dv.y, dv.z, dv.w};
        int ss[4] = {sv.x, sv.y, sv.z, sv.w};
#pragma unroll
        for (int j = 0; j < 4; j++) {
            int d = ds[j];
            int bin = d >> 8;
            myBin[j] = bin;
            myPack[j] = (u32)(ss[j] & 0xFFFF) | ((u32)(d & 0xFF) << 16);
            myRank[j] = atomicAdd(&cur[bin], 1);
        }
    }
    __syncthreads();
    int v = (t < NBINS) ? cur[t] : 0;
    int ex = block_exscan(v, scanbuf, t);
    if (t < NBINS) {
        lsStart[t] = ex;
        gbase[t] = (v > 0) ? (int)atomicAdd(&binCnt[t * 16], (u32)v) : 0;
    }
    __syncthreads();
    for (int j = 0; j < nmy; j++) {
        int bin = myBin[j];
        int idx = lsStart[bin] + myRank[j];
        int p = gbase[bin] + myRank[j];
        stage[idx] = myPack[j];
        gpos[idx] = (p < CAPB) ? (bin * CAPB + p) : -1;
    }
    __syncthreads();
    // write out in bin-sorted block order: lanes hit ascending positions within runs
    for (int i = t; i < nEdge; i += 256) {
        int p = gpos[i];
        if (p >= 0) binList[p] = stage[i];
    }
}

// ---------------- pass 2: build 256-node bucket slice in LDS, coalesced writeout ------
// bucket record (128B): word0 = degree count; u16 slots at bytes 4..127 (62 slots)
__global__ __launch_bounds__(256) void bucket_build(const u32* __restrict__ binList,
                                                    const u32* __restrict__ binCnt,
                                                    u32* __restrict__ bucket,
                                                    float* __restrict__ dis) {
    __shared__ u32 rec[256 * 32];  // 32 KB: 256 records of 128B
    int b = blockIdx.x, t = threadIdx.x;
    for (int i = t; i < 256 * 32; i += 256) rec[i] = 0;
    __syncthreads();
    int ecnt = min((int)binCnt[b * 16], CAPB);
    const u32* lst = binList + (size_t)b * CAPB;
    u16* rec16 = reinterpret_cast<u16*>(rec);
    for (int i = t; i < ecnt; i += 256) {
        u32 pk = lst[i];
        int dlow = (pk >> 16) & 0xFF;
        int pos = (int)atomicAdd(&rec[dlow * 32], 1u);
        if (pos < CAP) rec16[dlow * 64 + 2 + pos] = (u16)(pk & 0xFFFF);
    }
    __syncthreads();
    int node0 = b * 256;
    int nNode = min(256, N_NODES - node0);
    for (int i = t; i < nNode * 32; i += 256)
        bucket[(size_t)node0 * 32 + i] = rec[i];
    if (t < nNode) dis[node0 + t] = 1.0f / sqrtf((float)rec[t * 32] + 1.0f);
}

// ---------------- conversions ----------------
__global__ void convert_x_bf16(const float* __restrict__ x, u16* __restrict__ xb) {
    int i = blockIdx.x * 256 + threadIdx.x;  // one float4 per thread
    if (i >= (N_NODES * 128) / 4) return;
    float4 v = reinterpret_cast<const float4*>(x)[i];
    u32 lo = (u32)f2bf(v.x) | ((u32)f2bf(v.y) << 16);
    u32 hi = (u32)f2bf(v.z) | ((u32)f2bf(v.w) << 16);
    reinterpret_cast<uint2*>(xb)[i] = make_uint2(lo, hi);
}

// all four W[K][N] f32 -> Wt[N][K] bf16 transposes in one launch
__global__ void convert_wT_all(const float* __restrict__ W1, u16* __restrict__ wt1,
                               const float* __restrict__ W2, u16* __restrict__ wt2,
                               const float* __restrict__ W3, u16* __restrict__ wt3,
                               const float* __restrict__ W4, u16* __restrict__ wt4) {
    int idx = blockIdx.x * 256 + threadIdx.x;
    const float* Wf;
    u16* Wt;
    int K, N, off;
    if (idx < 16384)      { Wf = W1; Wt = wt1; K = 128; N = 128; off = 0; }
    else if (idx < 24576) { Wf = W2; Wt = wt2; K = 128; N = 64;  off = 16384; }
    else if (idx < 32768) { Wf = W3; Wt = wt3; K = 64;  N = 128; off = 24576; }
    else if (idx < 49152) { Wf = W4; Wt = wt4; K = 128; N = 128; off = 32768; }
    else return;
    int t = idx - off;
    int k = t / N, n = t % N;
    Wt[n * K + k] = f2bf(Wf[t]);
}

// ---------------- bf16 MFMA GEMM: C[M,N] = A[M,K] @ Wt[N,K]^T (+bias, relu, row-scale) --------
template <int N, int K, bool BIAS, bool RELU, bool SCALE>
__global__ __launch_bounds__(256) void gemm_mfma(const u16* __restrict__ A,
                                                 const u16* __restrict__ Wt,
                                                 const float* __restrict__ bias,
                                                 const float* __restrict__ dis,
                                                 u16* __restrict__ C) {
    constexpr int KB = K / 32;
    constexpr int TN = N / 64;
    constexpr int TM = (N_NODES + 63) / 64;  // 782
    int wave = threadIdx.x >> 6;
    int lane = threadIdx.x & 63;
    int W = blockIdx.x * 4 + wave;
    if (W >= TM * TN) return;
    int tm = W / TN, tn = W % TN;
    int r16 = lane & 15;
    int kg = lane >> 4;

    bf16x8_t bf[4][KB];
#pragma unroll
    for (int nr = 0; nr < 4; nr++) {
        int colg = tn * 64 + nr * 16 + r16;
#pragma unroll
        for (int kb = 0; kb < KB; kb++)
            bf[nr][kb] = *reinterpret_cast<const bf16x8_t*>(Wt + (size_t)colg * K + kb * 32 + kg * 8);
    }

    f32x4_t acc[4][4];
#pragma unroll
    for (int mr = 0; mr < 4; mr++)
#pragma unroll
        for (int nr = 0; nr < 4; nr++)
#pragma unroll
            for (int t = 0; t < 4; t++) acc[mr][nr][t] = 0.f;

#pragma unroll
    for (int mr = 0; mr < 4; mr++) {
        int row = tm * 64 + mr * 16 + r16;
        if (row >= N_NODES) row = N_NODES - 1;
        bf16x8_t af[KB];
#pragma unroll
        for (int kb = 0; kb < KB; kb++)
            af[kb] = *reinterpret_cast<const bf16x8_t*>(A + (size_t)row * K + kb * 32 + kg * 8);
#pragma unroll
        for (int kb = 0; kb < KB; kb++)
#pragma unroll
            for (int nr = 0; nr < 4; nr++)
                acc[mr][nr] = __builtin_amdgcn_mfma_f32_16x16x32_bf16(af[kb], bf[nr][kb],
                                                                      acc[mr][nr], 0, 0, 0);
    }

#pragma unroll
    for (int mr = 0; mr < 4; mr++) {
        float sc[4];
#pragma unroll
        for (int r = 0; r < 4; r++) {
            int row = tm * 64 + mr * 16 + kg * 4 + r;
            sc[r] = (SCALE && row < N_NODES) ? dis[row] : 1.f;
        }
#pragma unroll
        for (int nr = 0; nr < 4; nr++) {
            int colg = tn * 64 + nr * 16 + r16;
            float bv = BIAS ? bias[colg] : 0.f;
#pragma unroll
            for (int r = 0; r < 4; r++) {
                int row = tm * 64 + mr * 16 + kg * 4 + r;
                if (row < N_NODES) {
                    float v = acc[mr][nr][r] + bv;
                    if (RELU) v = fmaxf(v, 0.f);
                    if (SCALE) v *= sc[r];
                    C[(size_t)row * N + colg] = f2bf(v);
                }
            }
        }
    }
}

// ---------------- propagate over pre-scaled rows h' = dis ⊙ h ----------------
template <int F, bool RELU, bool BIAS, bool WF32, bool WBF16, bool SCALEOUT>
__global__ __launch_bounds__(256) void propagate_b(const u16* __restrict__ h,
                                                   const u32* __restrict__ bucket,
                                                   const float* __restrict__ dis,
                                                   const float* __restrict__ bias,
                                                   float* __restrict__ out_f,
                                                   u16* __restrict__ out_b) {
    int w = (blockIdx.x * blockDim.x + threadIdx.x) >> 6;
    int lane = threadIdx.x & 63;
    if (w >= N_NODES) return;
    const u32* bw = bucket + (size_t)w * 32;
    int deg = __builtin_amdgcn_readfirstlane(min((int)bw[0], CAP));
    const u16* slots = reinterpret_cast<const u16*>(bw) + 2;
    const u32* sw = reinterpret_cast<const u32*>(reinterpret_cast<const char*>(bw) + 4);
    float di = dis[w];

    if (F == 128) {
        const u32* hw = reinterpret_cast<const u32*>(h);  // 64 u32 per row
        float2 a0 = {0.f, 0.f}, a1 = {0.f, 0.f}, a2 = {0.f, 0.f}, a3 = {0.f, 0.f};
        int i = 0;
        for (; i + 16 <= deg; i += 16) {
            u32 cw[8], hv[16];
#pragma unroll
            for (int j = 0; j < 8; j++) cw[j] = sw[(i >> 1) + j];
#pragma unroll
            for (int j = 0; j < 8; j++) {
                hv[2 * j]     = hw[(size_t)(cw[j] & 0xffffu) * 64 + lane];
                hv[2 * j + 1] = hw[(size_t)(cw[j] >> 16) * 64 + lane];
            }
#pragma unroll
            for (int j = 0; j < 16; j++) {
                float lo = bf_lo(hv[j]), hi = bf_hi(hv[j]);
                if ((j & 3) == 0) { a0.x += lo; a0.y += hi; }
                else if ((j & 3) == 1) { a1.x += lo; a1.y += hi; }
                else if ((j & 3) == 2) { a2.x += lo; a2.y += hi; }
                else { a3.x += lo; a3.y += hi; }
            }
        }
        for (; i + 8 <= deg; i += 8) {
            u32 cw[4], hv[8];
#pragma unroll
            for (int j = 0; j < 4; j++) cw[j] = sw[(i >> 1) + j];
#pragma unroll
            for (int j = 0; j < 4; j++) {
                hv[2 * j]     = hw[(size_t)(cw[j] & 0xffffu) * 64 + lane];
                hv[2 * j + 1] = hw[(size_t)(cw[j] >> 16) * 64 + lane];
            }
#pragma unroll
            for (int j = 0; j < 8; j++) {
                float lo = bf_lo(hv[j]), hi = bf_hi(hv[j]);
                if ((j & 3) == 0) { a0.x += lo; a0.y += hi; }
                else if ((j & 3) == 1) { a1.x += lo; a1.y += hi; }
                else if ((j & 3) == 2) { a2.x += lo; a2.y += hi; }
                else { a3.x += lo; a3.y += hi; }
            }
        }
        for (; i < deg; i++) {
            u32 u = hw[(size_t)slots[i] * 64 + lane];
            a0.x += bf_lo(u);
            a0.y += bf_hi(u);
        }
        u32 su = hw[(size_t)w * 64 + lane];
        float ox = (a0.x + a1.x + a2.x + a3.x + bf_lo(su)) * di;
        float oy = (a0.y + a1.y + a2.y + a3.y + bf_hi(su)) * di;
        if (BIAS) {
            float2 bv = reinterpret_cast<const float2*>(bias)[lane];
            ox += bv.x;
            oy += bv.y;
        }
        if (RELU) { ox = fmaxf(ox, 0.f); oy = fmaxf(oy, 0.f); }
        if (WF32) {
            reinterpret_cast<float2*>(out_f + (size_t)w * 128)[lane] = make_float2(ox, oy);
        }
        if (WBF16) {
            float wx = SCALEOUT ? ox * di : ox;
            float wy = SCALEOUT ? oy * di : oy;
            u32 pk = (u32)f2bf(wx) | ((u32)f2bf(wy) << 16);
            reinterpret_cast<u32*>(out_b)[(size_t)w * 64 + lane] = pk;
        }
    } else {
        float a0 = 0.f, a1 = 0.f, a2 = 0.f, a3 = 0.f;
        int i = 0;
        for (; i + 16 <= deg; i += 16) {
            u32 cw[8];
            u16 hv[16];
#pragma unroll
            for (int j = 0; j < 8; j++) cw[j] = sw[(i >> 1) + j];
#pragma unroll
            for (int j = 0; j < 8; j++) {
                hv[2 * j]     = h[(size_t)(cw[j] & 0xffffu) * 64 + lane];
                hv[2 * j + 1] = h[(size_t)(cw[j] >> 16) * 64 + lane];
            }
#pragma unroll
            for (int j = 0; j < 16; j++) {
                float v = bf2f(hv[j]);
                if ((j & 3) == 0) a0 += v;
                else if ((j & 3) == 1) a1 += v;
                else if ((j & 3) == 2) a2 += v;
                else a3 += v;
            }
        }
        for (; i + 8 <= deg; i += 8) {
            u32 cw[4];
            u16 hv[8];
#pragma unroll
            for (int j = 0; j < 4; j++) cw[j] = sw[(i >> 1) + j];
#pragma unroll
            for (int j = 0; j < 4; j++) {
                hv[2 * j]     = h[(size_t)(cw[j] & 0xffffu) * 64 + lane];
                hv[2 * j + 1] = h[(size_t)(cw[j] >> 16) * 64 + lane];
            }
#pragma unroll
            for (int j = 0; j < 8; j++) {
                float v = bf2f(hv[j]);
                if ((j & 3) == 0) a0 += v;
                else if ((j & 3) == 1) a1 += v;
                else if ((j & 3) == 2) a2 += v;
                else a3 += v;
            }
        }
        for (; i < deg; i++) a0 += bf2f(h[(size_t)slots[i] * 64 + lane]);
        float o = (a0 + a1 + a2 + a3 + bf2f(h[(size_t)w * 64 + lane])) * di;
        if (BIAS) o += bias[lane];
        if (RELU) o = fmaxf(o, 0.f);
        if (WF32) out_f[(size_t)w * 64 + lane] = o;
        if (WBF16) out_b[(size_t)w * 64 + lane] = f2bf(SCALEOUT ? o * di : o);
    }
}

// ---------------- scatter-mean pooling: one block (4 waves) per graph ----------------
__global__ __launch_bounds__(256) void pool_kernel(const float* __restrict__ z,
                                                   const int* __restrict__ batch,
                                                   float* __restrict__ agg) {
    __shared__ float part[3][64];
    int g = blockIdx.x;
    int wave = threadIdx.x >> 6;
    int lane = threadIdx.x & 63;
    int l = 0, h = N_NODES;
    while (l < h) { int m = (l + h) >> 1; if (batch[m] < g) l = m + 1; else h = m; }
    int s = l;
    h = N_NODES;
    while (l < h) { int m = (l + h) >> 1; if (batch[m] < g + 1) l = m + 1; else h = m; }
    int e = l;
    float acc = 0.f;
    for (int i = s + wave; i < e; i += 4) acc += z[(size_t)i * 64 + lane];
    if (wave) part[wave - 1][lane] = acc;
    __syncthreads();
    if (wave == 0) {
        acc += part[0][lane] + part[1][lane] + part[2][lane];
        agg[(size_t)g * 64 + lane] = acc / fmaxf((float)(e - s), 1.0f);
    }
}

extern "C" void kernel_launch(void* const* d_in, const int* in_sizes, int n_in,
                              void* d_out, int out_size, void* d_ws, size_t ws_size,
                              hipStream_t stream) {
    const float* x   = (const float*)d_in[0];
    const int* eidx  = (const int*)d_in[1];
    const int* batch = (const int*)d_in[2];
    const float* W1  = (const float*)d_in[3];
    const float* b1  = (const float*)d_in[4];
    const float* W2  = (const float*)d_in[5];
    const float* b2  = (const float*)d_in[6];
    const float* W3  = (const float*)d_in[7];
    const float* b3  = (const float*)d_in[8];
    const float* W4  = (const float*)d_in[9];
    const float* b4  = (const float*)d_in[10];

    const int* src = eidx;
    const int* dst = eidx + N_EDGES;

    float* out_xhat = (float*)d_out;
    float* out_z    = out_xhat + (size_t)N_NODES * 128;
    float* out_agg  = out_z + (size_t)N_NODES * 64;

    char* p = (char*)d_ws;
    auto alloc = [&](size_t bytes) { char* r = p; p += (bytes + 255) & ~(size_t)255; return r; };
    u16* arena0 = (u16*)alloc((size_t)N_NODES * 128 * 2);   // 12.8 MB
    u16* arena1 = (u16*)alloc((size_t)N_NODES * 128 * 2);   // 12.8 MB
    u16* c1     = (u16*)alloc((size_t)N_NODES * 64 * 2);    // 6.4 MB
    u16* c2     = (u16*)alloc((size_t)N_NODES * 64 * 2);    // 6.4 MB
    u16* wt1    = (u16*)alloc(128 * 128 * 2);
    u16* wt2    = (u16*)alloc(128 * 64 * 2);
    u16* wt3    = (u16*)alloc(64 * 128 * 2);
    u16* wt4    = (u16*)alloc(128 * 128 * 2);
    u32* bucket = (u32*)alloc((size_t)N_NODES * 128);       // 6.4 MB, 128B records
    u32* binCnt = (u32*)alloc(NBINS * 16 * 4);              // padded: 1 counter / 64B
    u32* binList= (u32*)alloc((size_t)NBINS * CAPB * 4);    // 4.0 MB
    float* dis  = (float*)alloc(N_NODES * 4);

    // preprocessing: two-pass LDS-binned bucket build (no random global atomics/stores)
    hipMemsetAsync(binCnt, 0, NBINS * 16 * 4, stream);
    bin_scatter<<<NBLK_A, 256, 0, stream>>>(src, dst, binCnt, binList);
    bucket_build<<<NBINS, 256, 0, stream>>>(binList, binCnt, bucket, dis);

    convert_x_bf16<<<(N_NODES * 128 / 4 + 255) / 256, 256, 0, stream>>>(x, arena0);
    convert_wT_all<<<(49152 + 255) / 256, 256, 0, stream>>>(W1, wt1, W2, wt2, W3, wt3, W4, wt4);

    const int PROP_GRID = (N_NODES + 3) / 4;             // 12500
    const int G128 = ((N_NODES + 63) / 64 * 2 + 3) / 4;  // 391
    const int G64  = ((N_NODES + 63) / 64 * 1 + 3) / 4;  // 196

    // L1: C1' = dis ⊙ (x W1); h1 = relu(di*(Σ C1'[col] + C1'[w]) + b1)
    gemm_mfma<128, 128, false, false, true><<<G128, 256, 0, stream>>>(arena0, wt1, nullptr, dis, arena1);
    propagate_b<128, true, true, false, true, false><<<PROP_GRID, 256, 0, stream>>>(
        arena1, bucket, dis, b1, nullptr, arena0);
    // L2: C2' = dis ⊙ (h1 W2); z = di*(Σ C2'[col] + C2'[w]) + b2 ; c2 = dis ⊙ z (bf16)
    gemm_mfma<64, 128, false, false, true><<<G64, 256, 0, stream>>>(arena0, wt2, nullptr, dis, c1);
    propagate_b<64, false, true, true, true, true><<<PROP_GRID, 256, 0, stream>>>(
        c1, bucket, dis, b2, out_z, c2);
    pool_kernel<<<N_GRAPHS, 256, 0, stream>>>(out_z, batch, out_agg);
    // L3: t = P z  (gathers c2 = dis ⊙ z);  h2 = relu(t W3 + b3)
    propagate_b<64, false, false, false, true, false><<<PROP_GRID, 256, 0, stream>>>(
        c2, bucket, dis, nullptr, nullptr, c1);
    gemm_mfma<128, 64, true, true, false><<<G128, 256, 0, stream>>>(c1, wt3, b3, dis, arena1);
    // L4: C4' = dis ⊙ (h2 W4); x_hat = di*(Σ C4'[col] + C4'[w]) + b4
    gemm_mfma<128, 128, false, false, true><<<G128, 256, 0, stream>>>(arena1, wt4, nullptr, dis, arena0);
    propagate_b<128, false, true, true, false, false><<<PROP_GRID, 256, 0, stream>>>(
        arena0, bucket, dis, b4, out_xhat, nullptr);
}

// Round 10
// 258.108 us; speedup vs baseline: 1.4497x; 1.0346x over previous
//
#include <hip/hip_runtime.h>
#include <hip/hip_fp16.h>
#include <math.h>

#define N_NODES 50000
#define N_EDGES 800000
#define N_GRAPHS 512
#define CAP 62      // u16 slots per 128B bucket record; max degree (Poisson 16) ~45
#define NBINS 196   // bin = dst>>8 ; 196 bins of 256 nodes
#define CAPB 5120   // bin list capacity (expected 4081, sigma ~64)
#define ABLK 1024   // edges per bin_scatter block
#define PROP_BLOCKS 2048
#define PROP_WAVES (PROP_BLOCKS * 4)

typedef unsigned short u16;
typedef unsigned int u32;
typedef __attribute__((ext_vector_type(8))) short bf16x8_t;
typedef __attribute__((ext_vector_type(4))) float f32x4_t;
typedef __attribute__((ext_vector_type(4))) unsigned int u32x4_t;

constexpr int NBLK_A = (N_EDGES + ABLK - 1) / ABLK;  // 782
constexpr int NCW = (49152 + 255) / 256;             // 192 conv-W tail blocks

// ---- bf16 helpers (RTNE, finite values only) ----
__device__ __forceinline__ u16 f2bf(float f) {
    u32 u = __builtin_bit_cast(u32, f);
    return (u16)((u + 0x7fffu + ((u >> 16) & 1u)) >> 16);
}
__device__ __forceinline__ float bf2f(u16 s) {
    return __builtin_bit_cast(float, (u32)s << 16);
}
__device__ __forceinline__ float bf_lo(u32 u) { return __builtin_bit_cast(float, u << 16); }
__device__ __forceinline__ float bf_hi(u32 u) { return __builtin_bit_cast(float, u & 0xffff0000u); }

// convert 8 consecutive f32 -> bf16x8 fragment (RTNE)
__device__ __forceinline__ bf16x8_t cvt8(const float* p) {
    float4 a = *reinterpret_cast<const float4*>(p);
    float4 b = *reinterpret_cast<const float4*>(p + 4);
    u32x4_t w;
    w.x = (u32)f2bf(a.x) | ((u32)f2bf(a.y) << 16);
    w.y = (u32)f2bf(a.z) | ((u32)f2bf(a.w) << 16);
    w.z = (u32)f2bf(b.x) | ((u32)f2bf(b.y) << 16);
    w.w = (u32)f2bf(b.z) | ((u32)f2bf(b.w) << 16);
    return __builtin_bit_cast(bf16x8_t, w);
}

// ---------------- block-wide exclusive scan helper (256 threads) ----------------
__device__ __forceinline__ int block_exscan(int val, int* lds, int tid) {
    lds[tid] = val;
    __syncthreads();
#pragma unroll
    for (int off = 1; off < 256; off <<= 1) {
        int t = (tid >= off) ? lds[tid - off] : 0;
        __syncthreads();
        lds[tid] += t;
        __syncthreads();
    }
    return lds[tid] - val;
}

// ---------------- pass 1: bin edges by dst>>8 (+ convert_wT tail blocks) ----------------
// binCnt padded: counter b at binCnt[b*16] (one per 64B line).
__global__ __launch_bounds__(256) void pre_scatter(const int* __restrict__ src,
                                                   const int* __restrict__ dst,
                                                   u32* __restrict__ binCnt,
                                                   u32* __restrict__ binList,
                                                   const float* __restrict__ W1, u16* __restrict__ wt1,
                                                   const float* __restrict__ W2, u16* __restrict__ wt2,
                                                   const float* __restrict__ W3, u16* __restrict__ wt3,
                                                   const float* __restrict__ W4, u16* __restrict__ wt4) {
    __shared__ int cur[NBINS];
    __shared__ int lsStart[NBINS];
    __shared__ int gbase[NBINS];
    __shared__ int scanbuf[256];
    __shared__ u32 stage[ABLK];
    __shared__ int gpos[ABLK];
    int t = threadIdx.x;
    if (blockIdx.x >= NBLK_A) {
        // convert_wT tail: W[K][N] f32 -> Wt[N][K] bf16
        int idx = (blockIdx.x - NBLK_A) * 256 + t;
        const float* Wf;
        u16* Wt;
        int K, N, off;
        if (idx < 16384)      { Wf = W1; Wt = wt1; K = 128; N = 128; off = 0; }
        else if (idx < 24576) { Wf = W2; Wt = wt2; K = 128; N = 64;  off = 16384; }
        else if (idx < 32768) { Wf = W3; Wt = wt3; K = 64;  N = 128; off = 24576; }
        else                  { Wf = W4; Wt = wt4; K = 128; N = 128; off = 32768; }
        int q = idx - off;
        int k = q / N, n = q % N;
        Wt[n * K + k] = f2bf(Wf[q]);
        return;
    }
    int e0 = blockIdx.x * ABLK;
    int nEdge = min(ABLK, N_EDGES - e0);  // 1024 or 256 (last block), multiple of 4

    for (int i = t; i < NBINS; i += 256) cur[i] = 0;
    __syncthreads();

    int myBin[4], myRank[4];
    u32 myPack[4];
    int nmy = 0;
    if (t * 4 < nEdge) {
        nmy = 4;
        int4 dv = *reinterpret_cast<const int4*>(dst + e0 + t * 4);
        int4 sv = *reinterpret_cast<const int4*>(src + e0 + t * 4);
        int ds[4] = {dv.x, dv.y, dv.z, dv.w};
        int ss[4] = {sv.x, sv.y, sv.z, sv.w};
#pragma unroll
        for (int j = 0; j < 4; j++) {
            int d = ds[j];
            int bin = d >> 8;
            myBin[j] = bin;
            myPack[j] = (u32)(ss[j] & 0xFFFF) | ((u32)(d & 0xFF) << 16);
            myRank[j] = atomicAdd(&cur[bin], 1);
        }
    }
    __syncthreads();
    int v = (t < NBINS) ? cur[t] : 0;
    int ex = block_exscan(v, scanbuf, t);
    if (t < NBINS) {
        lsStart[t] = ex;
        gbase[t] = (v > 0) ? (int)atomicAdd(&binCnt[t * 16], (u32)v) : 0;
    }
    __syncthreads();
    for (int j = 0; j < nmy; j++) {
        int bin = myBin[j];
        int idx = lsStart[bin] + myRank[j];
        int p = gbase[bin] + myRank[j];
        stage[idx] = myPack[j];
        gpos[idx] = (p < CAPB) ? (bin * CAPB + p) : -1;
    }
    __syncthreads();
    for (int i = t; i < nEdge; i += 256) {
        int p = gpos[i];
        if (p >= 0) binList[p] = stage[i];
    }
}

// ---------------- pass 2: build 256-node bucket slice in LDS, coalesced writeout ------
// bucket record (128B): word0 = degree count; u16 slots at bytes 4..127 (62 slots)
__global__ __launch_bounds__(256) void bucket_build(const u32* __restrict__ binList,
                                                    const u32* __restrict__ binCnt,
                                                    u32* __restrict__ bucket,
                                                    float* __restrict__ dis) {
    __shared__ u32 rec[256 * 32];  // 32 KB: 256 records of 128B
    int b = blockIdx.x, t = threadIdx.x;
    for (int i = t; i < 256 * 32; i += 256) rec[i] = 0;
    __syncthreads();
    int ecnt = min((int)binCnt[b * 16], CAPB);
    const u32* lst = binList + (size_t)b * CAPB;
    u16* rec16 = reinterpret_cast<u16*>(rec);
    for (int i = t; i < ecnt; i += 256) {
        u32 pk = lst[i];
        int dlow = (pk >> 16) & 0xFF;
        int pos = (int)atomicAdd(&rec[dlow * 32], 1u);
        if (pos < CAP) rec16[dlow * 64 + 2 + pos] = (u16)(pk & 0xFFFF);
    }
    __syncthreads();
    int node0 = b * 256;
    int nNode = min(256, N_NODES - node0);
    for (int i = t; i < nNode * 32; i += 256)
        bucket[(size_t)node0 * 32 + i] = rec[i];
    if (t < nNode) dis[node0 + t] = 1.0f / sqrtf((float)rec[t * 32] + 1.0f);
}

// ---------------- bf16 MFMA GEMM: C[M,N] = A[M,K] @ Wt[N,K]^T (+bias, relu, row-scale) --------
// AF32: A is f32, converted to bf16 fragments in-register (saves a standalone convert pass).
template <int N, int K, bool BIAS, bool RELU, bool SCALE, bool AF32>
__global__ __launch_bounds__(256) void gemm_mfma(const void* __restrict__ Avp,
                                                 const u16* __restrict__ Wt,
                                                 const float* __restrict__ bias,
                                                 const float* __restrict__ dis,
                                                 u16* __restrict__ C) {
    constexpr int KB = K / 32;
    constexpr int TN = N / 64;
    constexpr int TM = (N_NODES + 63) / 64;  // 782
    int wave = threadIdx.x >> 6;
    int lane = threadIdx.x & 63;
    int W = blockIdx.x * 4 + wave;
    if (W >= TM * TN) return;
    int tm = W / TN, tn = W % TN;
    int r16 = lane & 15;
    int kg = lane >> 4;

    bf16x8_t bf[4][KB];
#pragma unroll
    for (int nr = 0; nr < 4; nr++) {
        int colg = tn * 64 + nr * 16 + r16;
#pragma unroll
        for (int kb = 0; kb < KB; kb++)
            bf[nr][kb] = *reinterpret_cast<const bf16x8_t*>(Wt + (size_t)colg * K + kb * 32 + kg * 8);
    }

    f32x4_t acc[4][4];
#pragma unroll
    for (int mr = 0; mr < 4; mr++)
#pragma unroll
        for (int nr = 0; nr < 4; nr++)
#pragma unroll
            for (int t = 0; t < 4; t++) acc[mr][nr][t] = 0.f;

#pragma unroll
    for (int mr = 0; mr < 4; mr++) {
        int row = tm * 64 + mr * 16 + r16;
        if (row >= N_NODES) row = N_NODES - 1;
        bf16x8_t af[KB];
#pragma unroll
        for (int kb = 0; kb < KB; kb++) {
            if constexpr (AF32) {
                const float* Af = (const float*)Avp;
                af[kb] = cvt8(Af + (size_t)row * K + kb * 32 + kg * 8);
            } else {
                const u16* Ab = (const u16*)Avp;
                af[kb] = *reinterpret_cast<const bf16x8_t*>(Ab + (size_t)row * K + kb * 32 + kg * 8);
            }
        }
#pragma unroll
        for (int kb = 0; kb < KB; kb++)
#pragma unroll
            for (int nr = 0; nr < 4; nr++)
                acc[mr][nr] = __builtin_amdgcn_mfma_f32_16x16x32_bf16(af[kb], bf[nr][kb],
                                                                      acc[mr][nr], 0, 0, 0);
    }

#pragma unroll
    for (int mr = 0; mr < 4; mr++) {
        float sc[4];
#pragma unroll
        for (int r = 0; r < 4; r++) {
            int row = tm * 64 + mr * 16 + kg * 4 + r;
            sc[r] = (SCALE && row < N_NODES) ? dis[row] : 1.f;
        }
#pragma unroll
        for (int nr = 0; nr < 4; nr++) {
            int colg = tn * 64 + nr * 16 + r16;
            float bv = BIAS ? bias[colg] : 0.f;
#pragma unroll
            for (int r = 0; r < 4; r++) {
                int row = tm * 64 + mr * 16 + kg * 4 + r;
                if (row < N_NODES) {
                    float v = acc[mr][nr][r] + bv;
                    if (RELU) v = fmaxf(v, 0.f);
                    if (SCALE) v *= sc[r];
                    C[(size_t)row * N + colg] = f2bf(v);
                }
            }
        }
    }
}

// ---------------- propagate over pre-scaled rows h' = dis ⊙ h (grid-stride) ----------------
template <int F, bool RELU, bool BIAS, bool WF32, bool WBF16, bool SCALEOUT>
__global__ __launch_bounds__(256) void propagate_b(const u16* __restrict__ h,
                                                   const u32* __restrict__ bucket,
                                                   const float* __restrict__ dis,
                                                   const float* __restrict__ bias,
                                                   float* __restrict__ out_f,
                                                   u16* __restrict__ out_b) {
    int wid = (blockIdx.x * 256 + threadIdx.x) >> 6;
    int lane = threadIdx.x & 63;
    // hoisted invariants
    float2 bv2 = make_float2(0.f, 0.f);
    float bv1 = 0.f;
    if (BIAS) {
        if (F == 128) bv2 = reinterpret_cast<const float2*>(bias)[lane];
        else          bv1 = bias[lane];
    }
    for (int w = wid; w < N_NODES; w += PROP_WAVES) {
        const u32* bw = bucket + (size_t)w * 32;
        int deg = __builtin_amdgcn_readfirstlane(min((int)bw[0], CAP));
        const u16* slots = reinterpret_cast<const u16*>(bw) + 2;
        const u32* sw = reinterpret_cast<const u32*>(reinterpret_cast<const char*>(bw) + 4);
        float di = dis[w];

        if (F == 128) {
            const u32* hw = reinterpret_cast<const u32*>(h);  // 64 u32 per row
            float2 a0 = {0.f, 0.f}, a1 = {0.f, 0.f}, a2 = {0.f, 0.f}, a3 = {0.f, 0.f};
            int i = 0;
            for (; i + 16 <= deg; i += 16) {
                u32 cw[8], hv[16];
#pragma unroll
                for (int j = 0; j < 8; j++) cw[j] = sw[(i >> 1) + j];
#pragma unroll
                for (int j = 0; j < 8; j++) {
                    hv[2 * j]     = hw[(size_t)(cw[j] & 0xffffu) * 64 + lane];
                    hv[2 * j + 1] = hw[(size_t)(cw[j] >> 16) * 64 + lane];
                }
#pragma unroll
                for (int j = 0; j < 16; j++) {
                    float lo = bf_lo(hv[j]), hi = bf_hi(hv[j]);
                    if ((j & 3) == 0) { a0.x += lo; a0.y += hi; }
                    else if ((j & 3) == 1) { a1.x += lo; a1.y += hi; }
                    else if ((j & 3) == 2) { a2.x += lo; a2.y += hi; }
                    else { a3.x += lo; a3.y += hi; }
                }
            }
            for (; i + 8 <= deg; i += 8) {
                u32 cw[4], hv[8];
#pragma unroll
                for (int j = 0; j < 4; j++) cw[j] = sw[(i >> 1) + j];
#pragma unroll
                for (int j = 0; j < 4; j++) {
                    hv[2 * j]     = hw[(size_t)(cw[j] & 0xffffu) * 64 + lane];
                    hv[2 * j + 1] = hw[(size_t)(cw[j] >> 16) * 64 + lane];
                }
#pragma unroll
                for (int j = 0; j < 8; j++) {
                    float lo = bf_lo(hv[j]), hi = bf_hi(hv[j]);
                    if ((j & 3) == 0) { a0.x += lo; a0.y += hi; }
                    else if ((j & 3) == 1) { a1.x += lo; a1.y += hi; }
                    else if ((j & 3) == 2) { a2.x += lo; a2.y += hi; }
                    else { a3.x += lo; a3.y += hi; }
                }
            }
            for (; i < deg; i++) {
                u32 u = hw[(size_t)slots[i] * 64 + lane];
                a0.x += bf_lo(u);
                a0.y += bf_hi(u);
            }
            u32 su = hw[(size_t)w * 64 + lane];
            float ox = (a0.x + a1.x + a2.x + a3.x + bf_lo(su)) * di;
            float oy = (a0.y + a1.y + a2.y + a3.y + bf_hi(su)) * di;
            if (BIAS) { ox += bv2.x; oy += bv2.y; }
            if (RELU) { ox = fmaxf(ox, 0.f); oy = fmaxf(oy, 0.f); }
            if (WF32) {
                reinterpret_cast<float2*>(out_f + (size_t)w * 128)[lane] = make_float2(ox, oy);
            }
            if (WBF16) {
                float wx = SCALEOUT ? ox * di : ox;
                float wy = SCALEOUT ? oy * di : oy;
                u32 pk = (u32)f2bf(wx) | ((u32)f2bf(wy) << 16);
                reinterpret_cast<u32*>(out_b)[(size_t)w * 64 + lane] = pk;
            }
        } else {
            float a0 = 0.f, a1 = 0.f, a2 = 0.f, a3 = 0.f;
            int i = 0;
            for (; i + 16 <= deg; i += 16) {
                u32 cw[8];
                u16 hv[16];
#pragma unroll
                for (int j = 0; j < 8; j++) cw[j] = sw[(i >> 1) + j];
#pragma unroll
                for (int j = 0; j < 8; j++) {
                    hv[2 * j]     = h[(size_t)(cw[j] & 0xffffu) * 64 + lane];
                    hv[2 * j + 1] = h[(size_t)(cw[j] >> 16) * 64 + lane];
                }
#pragma unroll
                for (int j = 0; j < 16; j++) {
                    float v = bf2f(hv[j]);
                    if ((j & 3) == 0) a0 += v;
                    else if ((j & 3) == 1) a1 += v;
                    else if ((j & 3) == 2) a2 += v;
                    else a3 += v;
                }
            }
            for (; i + 8 <= deg; i += 8) {
                u32 cw[4];
                u16 hv[8];
#pragma unroll
                for (int j = 0; j < 4; j++) cw[j] = sw[(i >> 1) + j];
#pragma unroll
                for (int j = 0; j < 4; j++) {
                    hv[2 * j]     = h[(size_t)(cw[j] & 0xffffu) * 64 + lane];
                    hv[2 * j + 1] = h[(size_t)(cw[j] >> 16) * 64 + lane];
                }
#pragma unroll
                for (int j = 0; j < 8; j++) {
                    float v = bf2f(hv[j]);
                    if ((j & 3) == 0) a0 += v;
                    else if ((j & 3) == 1) a1 += v;
                    else if ((j & 3) == 2) a2 += v;
                    else a3 += v;
                }
            }
            for (; i < deg; i++) a0 += bf2f(h[(size_t)slots[i] * 64 + lane]);
            float o = (a0 + a1 + a2 + a3 + bf2f(h[(size_t)w * 64 + lane])) * di;
            if (BIAS) o += bv1;
            if (RELU) o = fmaxf(o, 0.f);
            if (WF32) out_f[(size_t)w * 64 + lane] = o;
            if (WBF16) out_b[(size_t)w * 64 + lane] = f2bf(SCALEOUT ? o * di : o);
        }
    }
}

// ---------------- scatter-mean pooling: one block (4 waves) per graph ----------------
__global__ __launch_bounds__(256) void pool_kernel(const float* __restrict__ z,
                                                   const int* __restrict__ batch,
                                                   float* __restrict__ agg) {
    __shared__ float part[3][64];
    int g = blockIdx.x;
    int wave = threadIdx.x >> 6;
    int lane = threadIdx.x & 63;
    int l = 0, h = N_NODES;
    while (l < h) { int m = (l + h) >> 1; if (batch[m] < g) l = m + 1; else h = m; }
    int s = l;
    h = N_NODES;
    while (l < h) { int m = (l + h) >> 1; if (batch[m] < g + 1) l = m + 1; else h = m; }
    int e = l;
    float acc = 0.f;
    for (int i = s + wave; i < e; i += 4) acc += z[(size_t)i * 64 + lane];
    if (wave) part[wave - 1][lane] = acc;
    __syncthreads();
    if (wave == 0) {
        acc += part[0][lane] + part[1][lane] + part[2][lane];
        agg[(size_t)g * 64 + lane] = acc / fmaxf((float)(e - s), 1.0f);
    }
}

extern "C" void kernel_launch(void* const* d_in, const int* in_sizes, int n_in,
                              void* d_out, int out_size, void* d_ws, size_t ws_size,
                              hipStream_t stream) {
    const float* x   = (const float*)d_in[0];
    const int* eidx  = (const int*)d_in[1];
    const int* batch = (const int*)d_in[2];
    const float* W1  = (const float*)d_in[3];
    const float* b1  = (const float*)d_in[4];
    const float* W2  = (const float*)d_in[5];
    const float* b2  = (const float*)d_in[6];
    const float* W3  = (const float*)d_in[7];
    const float* b3  = (const float*)d_in[8];
    const float* W4  = (const float*)d_in[9];
    const float* b4  = (const float*)d_in[10];

    const int* src = eidx;
    const int* dst = eidx + N_EDGES;

    float* out_xhat = (float*)d_out;
    float* out_z    = out_xhat + (size_t)N_NODES * 128;
    float* out_agg  = out_z + (size_t)N_NODES * 64;

    char* p = (char*)d_ws;
    auto alloc = [&](size_t bytes) { char* r = p; p += (bytes + 255) & ~(size_t)255; return r; };
    u16* arena0 = (u16*)alloc((size_t)N_NODES * 128 * 2);   // 12.8 MB (h1)
    u16* arena1 = (u16*)alloc((size_t)N_NODES * 128 * 2);   // 12.8 MB
    u16* c1     = (u16*)alloc((size_t)N_NODES * 64 * 2);    // 6.4 MB
    u16* c2     = (u16*)alloc((size_t)N_NODES * 64 * 2);    // 6.4 MB
    u16* wt1    = (u16*)alloc(128 * 128 * 2);
    u16* wt2    = (u16*)alloc(128 * 64 * 2);
    u16* wt3    = (u16*)alloc(64 * 128 * 2);
    u16* wt4    = (u16*)alloc(128 * 128 * 2);
    u32* bucket = (u32*)alloc((size_t)N_NODES * 128);       // 6.4 MB, 128B records
    u32* binCnt = (u32*)alloc(NBINS * 16 * 4);              // padded: 1 counter / 64B
    u32* binList= (u32*)alloc((size_t)NBINS * CAPB * 4);    // 4.0 MB
    float* dis  = (float*)alloc(N_NODES * 4);

    // preprocessing: two-pass LDS-binned bucket build; convert_wT fused as tail blocks
    hipMemsetAsync(binCnt, 0, NBINS * 16 * 4, stream);
    pre_scatter<<<NBLK_A + NCW, 256, 0, stream>>>(src, dst, binCnt, binList,
                                                  W1, wt1, W2, wt2, W3, wt3, W4, wt4);
    bucket_build<<<NBINS, 256, 0, stream>>>(binList, binCnt, bucket, dis);

    const int G128 = ((N_NODES + 63) / 64 * 2 + 3) / 4;  // 391
    const int G64  = ((N_NODES + 63) / 64 * 1 + 3) / 4;  // 196

    // L1: C1' = dis ⊙ (x W1) [x read as f32, in-reg cvt]; h1 = relu(di*(Σ+self) + b1)
    gemm_mfma<128, 128, false, false, true, true><<<G128, 256, 0, stream>>>(
        x, wt1, nullptr, dis, arena1);
    propagate_b<128, true, true, false, true, false><<<PROP_BLOCKS, 256, 0, stream>>>(
        arena1, bucket, dis, b1, nullptr, arena0);
    // L2: C2' = dis ⊙ (h1 W2); z = di*(Σ+self) + b2 ; c2 = dis ⊙ z (bf16)
    gemm_mfma<64, 128, false, false, true, false><<<G64, 256, 0, stream>>>(
        arena0, wt2, nullptr, dis, c1);
    propagate_b<64, false, true, true, true, true><<<PROP_BLOCKS, 256, 0, stream>>>(
        c1, bucket, dis, b2, out_z, c2);
    pool_kernel<<<N_GRAPHS, 256, 0, stream>>>(out_z, batch, out_agg);
    // L3: t = P z  (gathers c2 = dis ⊙ z);  h2 = relu(t W3 + b3)
    propagate_b<64, false, false, false, true, false><<<PROP_BLOCKS, 256, 0, stream>>>(
        c2, bucket, dis, nullptr, nullptr, c1);
    gemm_mfma<128, 64, true, true, false, false><<<G128, 256, 0, stream>>>(
        c1, wt3, b3, dis, arena1);
    // L4: C4' = dis ⊙ (h2 W4); x_hat = di*(Σ+self) + b4
    gemm_mfma<128, 128, false, false, true, false><<<G128, 256, 0, stream>>>(
        arena1, wt4, nullptr, dis, arena0);
    propagate_b<128, false, true, true, false, false><<<PROP_BLOCKS, 256, 0, stream>>>(
        arena0, bucket, dis, b4, out_xhat, nullptr);
}